// Round 15
// baseline (495.584 us; speedup 1.0000x reference)
//
#include <hip/hip_runtime.h>

#define BB 512
#define SS 512
#define TT 78
#define TP 80
#define NT 64      // ONE wave per block: both chains (score+alpha) of one batch
#define LN2F 0.6931471805599453f

typedef _Float16 v2h __attribute__((ext_vector_type(2)));

template<int I> struct ic { static constexpr int v = I; };
template<int I, int N, typename F>
__device__ __forceinline__ void sfor(F f) {
    if constexpr (I < N) { f(ic<I>{}); sfor<I + 1, N>(f); }
}

__device__ __forceinline__ unsigned short f16b(float x) {
    return __builtin_bit_cast(unsigned short, (_Float16)x);
}

template<int CTRL>
__device__ __forceinline__ float dppmax(float v) {
    int vi = __builtin_bit_cast(int, v);
    int sh = __builtin_amdgcn_update_dpp(vi, vi, CTRL, 0xf, 0xf, false);
    return fmaxf(v, __builtin_bit_cast(float, sh));
}
// full 64-lane max via DPP (verified correct on HW in r13, absmax 0.0)
__device__ __forceinline__ float wave_max_dpp(float v) {
    v = dppmax<0x111>(v);   // row_shr:1
    v = dppmax<0x112>(v);   // row_shr:2
    v = dppmax<0x114>(v);   // row_shr:4
    v = dppmax<0x118>(v);   // row_shr:8
    v = dppmax<0x142>(v);   // row_bcast15
    v = dppmax<0x143>(v);   // row_bcast31 -> lane63 = full max
    int m = __builtin_amdgcn_readlane(__builtin_bit_cast(int, v), 63);
    return __builtin_bit_cast(float, m);
}

// r15: r14's 2-chains-per-wave structure (ILP latency hiding, 0 barriers,
// shared W/emissions) with the renorm done SAFELY: wave-max over POST-Em
// values (r14's lane0/pre-Em renorm overflowed f16 -> inf -> NaN), stored
// max in [1,2), exact int M2 scale ledger.
__global__ __attribute__((amdgpu_flat_work_group_size(NT, NT),
                          amdgpu_waves_per_eu(1, 1)))
void crf_fwd_kernel(const float* __restrict__ em,          // [B,S,T]
                    const unsigned int* __restrict__ mi32, // [B,S]
                    const float* __restrict__ st,
                    const float* __restrict__ en_,
                    const float* __restrict__ tr,          // [T,T]
                    float* __restrict__ out)               // [B]
{
    const int b    = blockIdx.x;
    const int lane = threadIdx.x;
    const bool has2 = lane < (TT - 64);
    const int  t0  = lane;
    const int  t1c = has2 ? (lane + 64) : (TT - 1);

    __shared__ __align__(16) unsigned short sE0[TP];  // score E (f16)
    __shared__ __align__(16) unsigned short sE1[TP];  // alpha E (f16)
    __shared__ int sflag;

    // ---- mask layout detection (int32 vs byte bools) ----
    if (lane == 0) sflag = 1;
    __syncthreads();
    { bool ok = true;
      for (int k = lane; k < 512; k += NT) ok = ok && (mi32[k] <= 1u);
      if (!ok) atomicAnd(&sflag, 0); }
    __syncthreads();
    const bool mask_int = (sflag != 0);
    const unsigned char* mi8 = (const unsigned char*)mi32;

    // ---- W = exp(trans) packed f16 pairs, SHARED by both chains: 80 VGPRs ----
    unsigned wt0[TP / 2], wt1[TP / 2];
    sfor<0, TP / 2>([&](auto P) {
        constexpr int p = decltype(P)::v;
        constexpr int j0 = 2 * p, j1 = 2 * p + 1;
        float a0 = (j0 < TT) ? __expf(tr[j0 * TT + t0])  : 0.f;
        float a1 = (j1 < TT) ? __expf(tr[j1 * TT + t0])  : 0.f;
        float b0 = (j0 < TT) ? __expf(tr[j0 * TT + t1c]) : 0.f;
        float b1 = (j1 < TT) ? __expf(tr[j1 * TT + t1c]) : 0.f;
        unsigned pa = (unsigned)f16b(a0) | ((unsigned)f16b(a1) << 16);
        unsigned pb = (unsigned)f16b(b0) | ((unsigned)f16b(b1) << 16);
        asm volatile("" : "+v"(pa), "+v"(pb));   // anti-remat fence (locals)
        wt0[p] = pa; wt1[p] = pb;
    });

    // ---- init: m0 = wave max of state0; stored E = exp(x - m0) <= 1 ----
    const size_t base = (size_t)b * SS * TT;
    float x0 = st[t0]  + em[base + t0];
    float x1 = st[t1c] + em[base + t1c];
    float m0 = wave_max_dpp(fmaxf(x0, has2 ? x1 : -1e30f));
    float s_e0 = __expf(x0 - m0);
    float s_e1 = __expf(x1 - m0);
    float a_e0 = s_e0, a_e1 = s_e1;
    int M2_s = 0, M2_a = 0;          // state = m0 + M2*ln2 + log(E)

    if (lane == 14 || lane == 15) { sE0[64 + lane] = 0; sE1[64 + lane] = 0; }
    sE0[lane] = f16b(s_e0);  sE1[lane] = f16b(a_e0);
    if (has2) { sE0[64 + lane] = f16b(s_e1); sE1[64 + lane] = f16b(a_e1); }

    // ---- prefetch step 1 (one emission/mask stream serves both chains) ----
    const float* rp = em + base + TT;
    float EmN0 = __expf(rp[t0]);
    float EmN1 = __expf(rp[t1c]);
    unsigned mk_n = mask_int ? mi32[b * SS + 1] : (unsigned)mi8[b * SS + 1];

    for (int i = 1; i < SS; ++i) {
        const float Em0 = EmN0, Em1 = EmN1;
        const unsigned mki = mk_n;
        if (i + 1 < SS) {
            rp += TT;
            EmN0 = __expf(rp[t0]);
            EmN1 = __expf(rp[t1c]);
            mk_n = mask_int ? mi32[b * SS + i + 1] : (unsigned)mi8[b * SS + i + 1];
        }
        __builtin_amdgcn_wave_barrier();

        // ---- both chains' dots interleaved (8 indep acc chains = ILP) ----
        const uint4* e0p = (const uint4*)sE0;
        const uint4* e1p = (const uint4*)sE1;
        float sa0 = 0.f, sa1 = 0.f, sc0 = 0.f, sc1 = 0.f;   // score t0/t1
        float aa0 = 0.f, aa1 = 0.f, ac0 = 0.f, ac1 = 0.f;   // alpha t0/t1
        sfor<0, TP / 8>([&](auto K) {
            constexpr int k = decltype(K)::v;
            uint4 q0 = e0p[k];
            uint4 q1 = e1p[k];
            sfor<0, 4>([&](auto J) {
                constexpr int j = decltype(J)::v;
                constexpr int p = 4 * k + j;
                unsigned u0 = (j == 0) ? q0.x : (j == 1) ? q0.y : (j == 2) ? q0.z : q0.w;
                unsigned u1 = (j == 0) ? q1.x : (j == 1) ? q1.y : (j == 2) ? q1.z : q1.w;
                v2h x0v = __builtin_bit_cast(v2h, u0);
                v2h x1v = __builtin_bit_cast(v2h, u1);
                v2h w0  = __builtin_bit_cast(v2h, wt0[p]);
                v2h w1  = __builtin_bit_cast(v2h, wt1[p]);
                if constexpr ((p & 1) == 0) {
                    sa0 = __builtin_amdgcn_fdot2(x0v, w0, sa0, false);
                    sc0 = __builtin_amdgcn_fdot2(x0v, w1, sc0, false);
                    aa0 = __builtin_amdgcn_fdot2(x1v, w0, aa0, false);
                    ac0 = __builtin_amdgcn_fdot2(x1v, w1, ac0, false);
                } else {
                    sa1 = __builtin_amdgcn_fdot2(x0v, w0, sa1, false);
                    sc1 = __builtin_amdgcn_fdot2(x0v, w1, sc1, false);
                    aa1 = __builtin_amdgcn_fdot2(x1v, w0, aa1, false);
                    ac1 = __builtin_amdgcn_fdot2(x1v, w1, ac1, false);
                }
            });
        });
        // ---- post-Em values FIRST, then renorm from their wave max ----
        float ns0 = (sa0 + sa1) * Em0, ns1 = (sc0 + sc1) * Em1;
        float na0 = (aa0 + aa1) * Em0, na1 = (ac0 + ac1) * Em1;

        float mxs = wave_max_dpp(fmaxf(ns0, has2 ? ns1 : 0.f));
        float mxa = wave_max_dpp(fmaxf(na0, has2 ? na1 : 0.f));
        int ds2 = (int)((__float_as_uint(mxs) >> 23) & 0xFF) - 127;
        int da2 = (int)((__float_as_uint(mxa) >> 23) & 0xFF) - 127;
        float ssc = __uint_as_float((unsigned)(127 - ds2) << 23);
        float asc = __uint_as_float((unsigned)(127 - da2) << 23);

        const bool updS = (mki != 0);
        s_e0 = updS ? ns0 * ssc : s_e0;
        s_e1 = updS ? ns1 * ssc : s_e1;
        M2_s = updS ? M2_s + ds2 : M2_s;
        a_e0 = na0 * asc; a_e1 = na1 * asc;
        M2_a += da2;

        __builtin_amdgcn_wave_barrier();
        sE0[lane] = f16b(s_e0);  sE1[lane] = f16b(a_e0);
        if (has2) { sE0[64 + lane] = f16b(s_e1); sE1[64 + lane] = f16b(a_e1); }
    }

    // ---- epilogue: per-chain LSE with end transitions, in-wave ----
    float fen0 = __expf(en_[t0]);
    float fen1 = __expf(en_[t1c]);
    float fss = s_e0 * fen0 + (has2 ? s_e1 * fen1 : 0.f);
    float fsa = a_e0 * fen0 + (has2 ? a_e1 * fen1 : 0.f);
    #pragma unroll
    for (int o = 32; o > 0; o >>= 1) {
        fss += __shfl_xor(fss, o);
        fsa += __shfl_xor(fsa, o);
    }
    if (lane == 0)
        out[b] = (__logf(fsa) + (float)M2_a * LN2F)
               - (__logf(fss) + (float)M2_s * LN2F);
}

extern "C" void kernel_launch(void* const* d_in, const int* in_sizes, int n_in,
                              void* d_out, int out_size, void* d_ws, size_t ws_size,
                              hipStream_t stream) {
    const float* emissions    = (const float*)d_in[0];
    const unsigned int* mask  = (const unsigned int*)d_in[1];
    const float* start_trans  = (const float*)d_in[2];
    const float* end_trans    = (const float*)d_in[3];
    const float* transitions  = (const float*)d_in[4];
    float* out = (float*)d_out;

    crf_fwd_kernel<<<BB, NT, 0, stream>>>(emissions, mask, start_trans,
                                          end_trans, transitions, out);
}

// Round 16
// 398.900 us; speedup vs baseline: 1.2424x; 1.2424x over previous
//
#include <hip/hip_runtime.h>

#define BB 512
#define SS 512
#define TT 78
#define NPAIR 39   // source-tag f16 pairs (78 tags)
#define NT 128     // 2 waves: wave0 = score chain, wave1 = alpha chain
#define LN2F 0.6931471805599453f

typedef _Float16 v2h __attribute__((ext_vector_type(2)));

template<int I> struct ic { static constexpr int v = I; };
template<int I, int N, typename F>
__device__ __forceinline__ void sfor(F f) {
    if constexpr (I < N) { f(ic<I>{}); sfor<I + 1, N>(f); }
}

__device__ __forceinline__ unsigned short f16b(float x) {
    return __builtin_bit_cast(unsigned short, (_Float16)x);
}

template<int CTRL>
__device__ __forceinline__ float dppmax(float v) {
    int vi = __builtin_bit_cast(int, v);
    int sh = __builtin_amdgcn_update_dpp(vi, vi, CTRL, 0xf, 0xf, false);
    return fmaxf(v, __builtin_bit_cast(float, sh));
}
// 64-lane max via DPP (HW-verified r13/r15, absmax 0.0)
__device__ __forceinline__ float wave_max_dpp(float v) {
    v = dppmax<0x111>(v); v = dppmax<0x112>(v); v = dppmax<0x114>(v);
    v = dppmax<0x118>(v); v = dppmax<0x142>(v); v = dppmax<0x143>(v);
    int m = __builtin_amdgcn_readlane(__builtin_bit_cast(int, v), 63);
    return __builtin_bit_cast(float, m);
}
// quad_perm [1,0,3,2]: even lane <- odd neighbor's value
__device__ __forceinline__ float quad_swap1(float v) {
    int vi = __builtin_bit_cast(int, v);
    int sh = __builtin_amdgcn_update_dpp(vi, vi, 0xB1, 0xf, 0xf, false);
    return __builtin_bit_cast(float, sh);
}
__device__ __forceinline__ v2h pack_pair(float a, float b) {
    return __builtin_bit_cast(v2h, __builtin_amdgcn_cvt_pkrtz(a, b));
}

// r16: ZERO-MEMORY inner loop. r9/r13/r15 fit: exposed stall ~= (#LDS reads
// on dep path) x ~120cyc — the compiler only keeps ~2 reads in flight at its
// 132-reg budget, serializing the E broadcast. Fix: E[j] is wave-uniform, so
// broadcast via v_readlane (constant lane) from the OWNING lanes' registers:
// 39 readlane + 78 fdot2 per step, no loads at all (em/mask prefetch
// off-path). Repack for next step = 2 DPP quad-swaps + 2 cvt_pkrtz.
__global__ __attribute__((amdgpu_flat_work_group_size(NT, NT)))
void crf_fwd_kernel(const float* __restrict__ em,          // [B,S,T]
                    const unsigned int* __restrict__ mi32, // [B,S]
                    const float* __restrict__ st,
                    const float* __restrict__ en_,
                    const float* __restrict__ tr,          // [T,T]
                    float* __restrict__ out)               // [B]
{
    const int b    = blockIdx.x;
    const int tid  = threadIdx.x;
    const int w    = tid >> 6;            // 0 = score (masked), 1 = alpha
    const int lane = tid & 63;
    const bool has2 = lane < (TT - 64);   // lanes 0..13 own tags 64..77
    const int  t0  = lane;
    const int  t1c = has2 ? (lane + 64) : (TT - 1);

    __shared__ float sfin[2];
    __shared__ int sflag;

    // ---- mask layout detection (int32 vs byte bools) ----
    if (tid == 0) sflag = 1;
    __syncthreads();
    { bool ok = true;
      for (int k = tid; k < 512; k += NT) ok = ok && (mi32[k] <= 1u);
      if (!ok) atomicAnd(&sflag, 0); }
    __syncthreads();
    const bool mask_int = (sflag != 0);
    const unsigned char* mi8 = (const unsigned char*)mi32;
    const bool is_alpha = (w == 1);

    // ---- W columns for my 2 target tags, f16 pairs: 78 VGPRs ----
    unsigned wt0[NPAIR], wt1[NPAIR];   // wt0[p] = {W[2p][t0], W[2p+1][t0]}
    sfor<0, NPAIR>([&](auto P) {
        constexpr int p = decltype(P)::v;
        constexpr int j0 = 2 * p, j1 = 2 * p + 1;   // both < 78
        float a0 = __expf(tr[j0 * TT + t0]);
        float a1 = __expf(tr[j1 * TT + t0]);
        float b0 = __expf(tr[j0 * TT + t1c]);
        float b1 = __expf(tr[j1 * TT + t1c]);
        unsigned pa = (unsigned)f16b(a0) | ((unsigned)f16b(a1) << 16);
        unsigned pb = (unsigned)f16b(b0) | ((unsigned)f16b(b1) << 16);
        asm volatile("" : "+v"(pa), "+v"(pb));   // anti-remat fence
        wt0[p] = pa; wt1[p] = pb;
    });

    // ---- init: f32 masters me0 (tag=lane), me1 (tag=64+lane, lanes<14) ----
    const size_t base = (size_t)b * SS * TT;
    float x0 = st[t0]  + em[base + t0];
    float x1 = st[t1c] + em[base + t1c];
    float m0 = wave_max_dpp(fmaxf(x0, has2 ? x1 : -1e30f));
    float me0 = __expf(x0 - m0);
    float me1 = has2 ? __expf(x1 - m0) : 0.f;
    int M2 = 0;                       // chain scale ledger (m0 cancels in diff)
    v2h pk0 = pack_pair(me0, quad_swap1(me0));  // even lane 2p: (E[2p],E[2p+1])
    v2h pk1 = pack_pair(me1, quad_swap1(me1));  // even lane 2q: (E[64+2q],E[64+2q+1])

    // ---- prefetch step 1 (off critical path) ----
    const float* rp = em + base + TT;
    float EmN0 = __expf(rp[t0]);
    float EmN1 = __expf(rp[t1c]);
    unsigned mk_n = mask_int ? mi32[b * SS + 1] : (unsigned)mi8[b * SS + 1];

    for (int i = 1; i < SS; ++i) {
        const float Em0 = EmN0, Em1 = EmN1;
        const unsigned mki = mk_n;
        if (i + 1 < SS) {
            rp += TT;
            EmN0 = __expf(rp[t0]);
            EmN1 = __expf(rp[t1c]);
            mk_n = mask_int ? mi32[b * SS + i + 1] : (unsigned)mi8[b * SS + i + 1];
        }

        // ---- matvec: readlane-broadcast E pairs -> fdot2 (no memory!) ----
        const int ipk0 = __builtin_bit_cast(int, pk0);
        const int ipk1 = __builtin_bit_cast(int, pk1);
        float a0 = 0.f, a1 = 0.f, c0 = 0.f, c1 = 0.f;
        sfor<0, 32>([&](auto P) {                  // source tags 0..63
            constexpr int p = decltype(P)::v;
            int r = __builtin_amdgcn_readlane(ipk0, 2 * p);
            v2h e = __builtin_bit_cast(v2h, r);
            v2h w0 = __builtin_bit_cast(v2h, wt0[p]);
            v2h w1 = __builtin_bit_cast(v2h, wt1[p]);
            if constexpr ((p & 1) == 0) {
                a0 = __builtin_amdgcn_fdot2(e, w0, a0, false);
                c0 = __builtin_amdgcn_fdot2(e, w1, c0, false);
            } else {
                a1 = __builtin_amdgcn_fdot2(e, w0, a1, false);
                c1 = __builtin_amdgcn_fdot2(e, w1, c1, false);
            }
        });
        sfor<0, 7>([&](auto Q) {                   // source tags 64..77
            constexpr int q = decltype(Q)::v;
            constexpr int p = 32 + q;
            int r = __builtin_amdgcn_readlane(ipk1, 2 * q);
            v2h e = __builtin_bit_cast(v2h, r);
            v2h w0 = __builtin_bit_cast(v2h, wt0[p]);
            v2h w1 = __builtin_bit_cast(v2h, wt1[p]);
            if constexpr ((q & 1) == 0) {
                a0 = __builtin_amdgcn_fdot2(e, w0, a0, false);
                c0 = __builtin_amdgcn_fdot2(e, w1, c0, false);
            } else {
                a1 = __builtin_amdgcn_fdot2(e, w0, a1, false);
                c1 = __builtin_amdgcn_fdot2(e, w1, c1, false);
            }
        });
        float n0 = (a0 + a1) * Em0;
        float n1 = has2 ? (c0 + c1) * Em1 : 0.f;

        // ---- renorm: wave-max POST-Em (safe; r13/r15-verified), pow2 ----
        float mx = wave_max_dpp(fmaxf(n0, n1));
        int d2 = (int)((__float_as_uint(mx) >> 23) & 0xFF) - 127;
        float scl = __uint_as_float((unsigned)(127 - d2) << 23);

        const bool upd = is_alpha | (mki != 0);
        me0 = upd ? n0 * scl : me0;
        me1 = upd ? n1 * scl : me1;
        M2  = upd ? M2 + d2 : M2;

        // ---- repack f16 pair copies for next step's readlanes ----
        pk0 = pack_pair(me0, quad_swap1(me0));
        pk1 = pack_pair(me1, quad_swap1(me1));
    }

    // ---- final: per-chain LSE with end transitions ----
    float fs = me0 * __expf(en_[t0]);
    if (has2) fs += me1 * __expf(en_[t1c]);
    #pragma unroll
    for (int o = 32; o > 0; o >>= 1) fs += __shfl_xor(fs, o);
    if (lane == 0) sfin[w] = __logf(fs) + (float)M2 * LN2F;
    __syncthreads();
    if (tid == 0) out[b] = sfin[1] - sfin[0];   // partition - score
}

extern "C" void kernel_launch(void* const* d_in, const int* in_sizes, int n_in,
                              void* d_out, int out_size, void* d_ws, size_t ws_size,
                              hipStream_t stream) {
    const float* emissions    = (const float*)d_in[0];
    const unsigned int* mask  = (const unsigned int*)d_in[1];
    const float* start_trans  = (const float*)d_in[2];
    const float* end_trans    = (const float*)d_in[3];
    const float* transitions  = (const float*)d_in[4];
    float* out = (float*)d_out;

    crf_fwd_kernel<<<BB, NT, 0, stream>>>(emissions, mask, start_trans,
                                          end_trans, transitions, out);
}

// Round 17
// 221.574 us; speedup vs baseline: 2.2367x; 1.8003x over previous
//
#include <hip/hip_runtime.h>

#define BB 512
#define SS 512
#define TT 78
#define TP 80
#define NT 256     // 4 waves: (chain: score/alpha) x (dir: fwd/bwd)
#define MID 255    // fwd covers steps 1..255; bwd covers 511..256
#define LN2F 0.6931471805599453f

typedef float v2f __attribute__((ext_vector_type(2)));
typedef float v4f __attribute__((ext_vector_type(4)));

template<int I> struct ic { static constexpr int v = I; };
template<int I, int N, typename F>
__device__ __forceinline__ void sfor(F f) {
    if constexpr (I < N) { f(ic<I>{}); sfor<I + 1, N>(f); }
}

// r17: SEQUENTIAL-DEPTH split. The DP is a chain of linear ops
// A_i = m_i ? W*diag(exp(em_i)) : I; associativity => evaluate from both ends:
// answer = log(v_mid . u_mid). 4 independent chains/batch = 2048 waves =
// 2/SIMD (latency hiding r9 never had) x depth 511->256. Engine = r9's
// verified fp32 matvec (201us, absmax 0.0). Backward uses W ROWS (u' = W(em.u)).
__global__ __attribute__((amdgpu_flat_work_group_size(NT, NT),
                          amdgpu_waves_per_eu(2, 2)))
void crf_fwd_kernel(const float* __restrict__ em,          // [B,S,T]
                    const unsigned int* __restrict__ mi32, // [B,S]
                    const float* __restrict__ st,
                    const float* __restrict__ en_,
                    const float* __restrict__ tr,          // [T,T]
                    float* __restrict__ out)               // [B]
{
    const int b    = blockIdx.x;
    const int tid  = threadIdx.x;
    const int w    = tid >> 6;
    const int lane = tid & 63;
    const int  chain   = w >> 1;          // 0 = score (masked), 1 = alpha
    const bool is_bwd  = (w & 1) != 0;
    const bool is_alpha = (chain == 1);
    const bool has2 = lane < (TT - 64);
    const int  t0  = lane;
    const int  t1c = has2 ? (lane + 64) : (TT - 1);

    __shared__ __align__(16) float sE[4][TP];   // per-wave state vector
    __shared__ float sRes[2];
    __shared__ int   sM2[4];
    __shared__ int   sflag;

    // ---- mask layout detection (int32 vs byte bools) ----
    if (tid == 0) sflag = 1;
    __syncthreads();
    { bool ok = true;
      for (int k = tid; k < 512; k += NT) ok = ok && (mi32[k] <= 1u);
      if (!ok) atomicAnd(&sflag, 0); }
    __syncthreads();
    const bool mask_int = (sflag != 0);
    const unsigned char* mi8 = (const unsigned char*)mi32;

    // ---- W: fwd waves hold COLUMNS W[.][t]; bwd waves hold ROWS W[t][.] ----
    v2f W0[TP / 2], W1[TP / 2];
    sfor<0, TP / 2>([&](auto P) {
        constexpr int p = decltype(P)::v;
        constexpr int j0 = 2 * p, j1 = 2 * p + 1;
        float a0 = 0.f, a1 = 0.f, b0 = 0.f, b1 = 0.f;
        if constexpr (j0 < TT) {
            a0 = __expf(tr[is_bwd ? (t0 * TT + j0)  : (j0 * TT + t0)]);
            b0 = __expf(tr[is_bwd ? (t1c * TT + j0) : (j0 * TT + t1c)]);
        }
        if constexpr (j1 < TT) {
            a1 = __expf(tr[is_bwd ? (t0 * TT + j1)  : (j1 * TT + t0)]);
            b1 = __expf(tr[is_bwd ? (t1c * TT + j1) : (j1 * TT + t1c)]);
        }
        asm volatile("" : "+v"(a0), "+v"(a1), "+v"(b0), "+v"(b1));
        W0[p] = (v2f){a0, a1};
        W1[p] = (v2f){b0, b1};
    });

    auto matvec = [&](float& v0, float& v1) {
        const v4f* ep = (const v4f*)sE[w];
        v2f a0{0.f, 0.f}, a1{0.f, 0.f}, c0{0.f, 0.f}, c1{0.f, 0.f};
        sfor<0, TP / 4>([&](auto K) {
            constexpr int k = decltype(K)::v;
            v4f x = ep[k];
            a0 = __builtin_elementwise_fma((v2f){x.x, x.y}, W0[2 * k],     a0);
            a1 = __builtin_elementwise_fma((v2f){x.z, x.w}, W0[2 * k + 1], a1);
            c0 = __builtin_elementwise_fma((v2f){x.x, x.y}, W1[2 * k],     c0);
            c1 = __builtin_elementwise_fma((v2f){x.z, x.w}, W1[2 * k + 1], c1);
        });
        v2f va = a0 + a1, vc = c0 + c1;
        v0 = va.x + va.y;
        v1 = vc.x + vc.y;
    };

    const size_t base = (size_t)b * SS * TT;
    float e0, e1;
    int M2 = 0;
    if (lane == 14 || lane == 15) sE[w][64 + lane] = 0.f;   // pads 78,79

    if (!is_bwd) {
        // ================= FORWARD: steps 1..MID =================
        e0 = __expf(st[t0]  + em[base + t0]);
        e1 = __expf(st[t1c] + em[base + t1c]);
        sE[w][t0] = e0;
        if (has2) sE[w][64 + lane] = e1;

        const float* rp = em + base + TT;
        float EmN0 = __expf(rp[t0]);
        float EmN1 = __expf(rp[t1c]);
        unsigned mk_n = mask_int ? mi32[b * SS + 1] : (unsigned)mi8[b * SS + 1];

        for (int i = 1; i <= MID; ++i) {
            const float Em0 = EmN0, Em1 = EmN1;
            const unsigned mki = mk_n;
            if (i < MID) {
                rp += TT;
                EmN0 = __expf(rp[t0]);
                EmN1 = __expf(rp[t1c]);
                mk_n = mask_int ? mi32[b * SS + i + 1] : (unsigned)mi8[b * SS + i + 1];
            }
            __builtin_amdgcn_wave_barrier();
            float v0, v1; matvec(v0, v1);
            float vref = __builtin_amdgcn_readfirstlane(v0);
            int d2 = (int)((__float_as_uint(vref) >> 23) & 0xFF) - 127;
            float scl = __uint_as_float((unsigned)(127 - d2) << 23);
            float n0 = v0 * scl * Em0;
            float n1 = v1 * scl * Em1;
            const bool upd = is_alpha | (mki != 0);
            e0 = upd ? n0 : e0;
            e1 = upd ? n1 : e1;
            M2 = upd ? M2 + d2 : M2;
            __builtin_amdgcn_wave_barrier();
            sE[w][t0] = e0;
            if (has2) sE[w][64 + lane] = e1;
        }
        // sE[w] = v_mid
    } else {
        // ================= BACKWARD: steps SS-1 .. MID+1 =================
        // u_{i-1} = m_i ? W (em_i . u_i) : u_i ;  stored vec = f = em . u
        e0 = __expf(en_[t0]);
        e1 = __expf(en_[t1c]);
        const float* rp = em + base + (size_t)(SS - 1) * TT;
        sE[w][t0] = e0 * __expf(rp[t0]);
        if (has2) sE[w][64 + lane] = e1 * __expf(rp[t1c]);

        unsigned mk_n = mask_int ? mi32[b * SS + SS - 1]
                                 : (unsigned)mi8[b * SS + SS - 1];
        rp -= TT;
        float EmN0 = __expf(rp[t0]);
        float EmN1 = __expf(rp[t1c]);

        for (int i = SS - 1; i > MID; --i) {
            const unsigned mki = mk_n;
            const float Em0 = (i - 1 > MID) ? EmN0 : 1.0f;
            const float Em1 = (i - 1 > MID) ? EmN1 : 1.0f;
            if (i - 1 > MID) {
                mk_n = mask_int ? mi32[b * SS + i - 1] : (unsigned)mi8[b * SS + i - 1];
                if (i - 2 > MID) {
                    rp -= TT;
                    EmN0 = __expf(rp[t0]);
                    EmN1 = __expf(rp[t1c]);
                }
            }
            __builtin_amdgcn_wave_barrier();
            float y0, y1; matvec(y0, y1);
            float vref = __builtin_amdgcn_readfirstlane(y0);
            int d2 = (int)((__float_as_uint(vref) >> 23) & 0xFF) - 127;
            float scl = __uint_as_float((unsigned)(127 - d2) << 23);
            const bool upd = is_alpha | (mki != 0);
            e0 = upd ? y0 * scl : e0;
            e1 = upd ? y1 * scl : e1;
            M2 = upd ? M2 + d2 : M2;
            float nf0 = e0 * Em0;       // last iter: Em=1 -> sE = u_mid
            float nf1 = e1 * Em1;
            __builtin_amdgcn_wave_barrier();
            sE[w][t0] = nf0;
            if (has2) sE[w][64 + lane] = nf1;
        }
        // sE[w] = u_mid
    }

    // ---- combine: per chain, log(v_mid . u_mid) + (M2f+M2b)ln2 ----
    if (lane == 0) sM2[w] = M2;
    __syncthreads();
    if (!is_bwd) {
        float d = e0 * sE[w + 1][t0];
        if (has2) d += e1 * sE[w + 1][64 + lane];
        #pragma unroll
        for (int o = 32; o > 0; o >>= 1) d += __shfl_xor(d, o);
        if (lane == 0)
            sRes[chain] = __logf(d) + (float)(M2 + sM2[w + 1]) * LN2F;
    }
    __syncthreads();
    if (tid == 0) out[b] = sRes[1] - sRes[0];   // partition - score
}

extern "C" void kernel_launch(void* const* d_in, const int* in_sizes, int n_in,
                              void* d_out, int out_size, void* d_ws, size_t ws_size,
                              hipStream_t stream) {
    const float* emissions    = (const float*)d_in[0];
    const unsigned int* mask  = (const unsigned int*)d_in[1];
    const float* start_trans  = (const float*)d_in[2];
    const float* end_trans    = (const float*)d_in[3];
    const float* transitions  = (const float*)d_in[4];
    float* out = (float*)d_out;

    crf_fwd_kernel<<<BB, NT, 0, stream>>>(emissions, mask, start_trans,
                                          end_trans, transitions, out);
}